// Round 2
// baseline (659.781 us; speedup 1.0000x reference)
//
#include <hip/hip_runtime.h>
#include <hip/hip_bf16.h>

#define T_TOK 16384
#define H_DIM 1024
#define I_DIM 1024
#define E_NUM 8
#define NPAIR (T_TOK * 2)
#define BM 256
#define BK 64
#define KITER 16                        // K = 1024 for both GEMMs
#define MAX_MT (NPAIR / BM + E_NUM)     // 136 worst-case 256-row tiles

typedef float v4f __attribute__((ext_vector_type(4)));
typedef float v16f __attribute__((ext_vector_type(16)));
typedef short v8s __attribute__((ext_vector_type(8)));

__device__ __forceinline__ unsigned short f2bf(float f) {
    unsigned int u = __float_as_uint(f);
    unsigned int r = (u + 0x7fffu + ((u >> 16) & 1u)) >> 16;   // RNE
    return (unsigned short)r;
}
__device__ __forceinline__ float bf2f(unsigned short s) {
    return __uint_as_float(((unsigned int)s) << 16);
}

__device__ __forceinline__ void gl_lds16(const void* g, void* l) {
    __builtin_amdgcn_global_load_lds(
        (const __attribute__((address_space(1))) void*)g,
        (__attribute__((address_space(3))) void*)l, 16, 0, 0);
}

// XOR-swizzled LDS tile: row-major [rows][64 bf16], each row's eight 16B units
// xor'd by (row&7). Staged by swizzling the GLOBAL source column per lane.
__device__ __forceinline__ int swz(int row, int unit) {
    return row * 64 + ((unit ^ (row & 7)) << 3);
}

// chunk -> 8-row block maps. A: chunks {0,1} cover M-half0 rows {0-63,128-191}
// (= per-wave rows wm*128+0..63), chunks {2,3} cover M-half1 {64-127,192-255}.
// B: chunks {0,1} cover N-half0 rows {0-31,64-95,128-159,192-223} (= every
// wave's b0 rows), {2,3} the b1 complement. Staged halves are therefore
// always disjoint from same-phase reads.
__device__ __forceinline__ int blkA_of(int w, int j) {
    int idx = 2 * w + (j & 1);
    int blk = idx + ((idx >= 8) ? 8 : 0);
    return blk + ((j >= 2) ? 8 : 0);
}
__device__ __forceinline__ int blkB_of(int w, int j) {
    int idx = 2 * w + (j & 1);
    int blk = (idx >> 2) * 8 + (idx & 3);
    return blk + ((j >= 2) ? 4 : 0);
}

__device__ __forceinline__ void rd_a(const unsigned short* lAc, int rbase, int lane, v8s a[2][4]) {
#pragma unroll
    for (int i = 0; i < 2; i++)
#pragma unroll
        for (int ks = 0; ks < 4; ks++)
            a[i][ks] = *(const v8s*)(lAc + swz(rbase + i * 32 + (lane & 31), 2 * ks + (lane >> 5)));
}
__device__ __forceinline__ void rd_b(const unsigned short* lBc, int rbase, int lane, v8s b[4]) {
#pragma unroll
    for (int ks = 0; ks < 4; ks++)
        b[ks] = *(const v8s*)(lBc + swz(rbase + (lane & 31), 2 * ks + (lane >> 5)));
}
__device__ __forceinline__ void mfma8(const v8s a[2][4], const v8s b[4], v16f* c0, v16f* c1) {
#pragma unroll
    for (int ks = 0; ks < 4; ks++) {
        *c0 = __builtin_amdgcn_mfma_f32_32x32x16_bf16(a[0][ks], b[ks], *c0, 0, 0, 0);
        *c1 = __builtin_amdgcn_mfma_f32_32x32x16_bf16(a[1][ks], b[ks], *c1, 0, 0, 0);
    }
}

// ---------------- routing ----------------
__global__ void k_route(const float* __restrict__ gating,
                        int* __restrict__ tokExp, float* __restrict__ tokW,
                        int* __restrict__ counts) {
    int t = blockIdx.x * 256 + threadIdx.x;
    int lane = threadIdx.x & 63;
    float g[E_NUM];
#pragma unroll
    for (int e = 0; e < E_NUM; e++) g[e] = gating[t * E_NUM + e];
    int i0 = 0; float v0 = g[0];
#pragma unroll
    for (int e = 1; e < E_NUM; e++) if (g[e] > v0) { v0 = g[e]; i0 = e; }
    int i1 = -1; float v1 = -1e30f;
#pragma unroll
    for (int e = 0; e < E_NUM; e++) if (e != i0 && g[e] > v1) { v1 = g[e]; i1 = e; }
    float w0 = 1.f / (1.f + __expf(v1 - v0));   // renormalized top-2
    tokExp[2 * t] = i0; tokExp[2 * t + 1] = i1;
    tokW[2 * t] = w0;   tokW[2 * t + 1] = 1.f - w0;
#pragma unroll
    for (int e = 0; e < E_NUM; e++) {
        unsigned long long mA = __ballot(i0 == e);
        unsigned long long mB = __ballot(i1 == e);
        int c = __popcll(mA) + __popcll(mB);
        if (lane == 0 && c) atomicAdd(&counts[e], c);
    }
}

__global__ void k_scan(const int* __restrict__ counts, int* __restrict__ offsets,
                       int* __restrict__ tileOff, int* __restrict__ cursor) {
    if (threadIdx.x == 0 && blockIdx.x == 0) {
        int o = 0, to = 0;
        for (int e = 0; e < E_NUM; e++) {
            offsets[e] = o; tileOff[e] = to; cursor[e] = o;
            o += counts[e];
            to += (counts[e] + BM - 1) / BM;
        }
        offsets[E_NUM] = o; tileOff[E_NUM] = to;
    }
}

__global__ void k_scatter(const int* __restrict__ tokExp, const float* __restrict__ tokW,
                          int* __restrict__ cursor,
                          int* __restrict__ pairTok, float* __restrict__ pairW,
                          int* __restrict__ invMap) {
    int t = blockIdx.x * 256 + threadIdx.x;
    int lane = threadIdx.x & 63;
#pragma unroll
    for (int k = 0; k < 2; k++) {
        int e = tokExp[2 * t + k];
        int pos = 0;
#pragma unroll
        for (int ex = 0; ex < E_NUM; ex++) {
            unsigned long long m = __ballot(e == ex);
            if (m) {
                int leader = __builtin_ctzll(m);
                int base = 0;
                if (lane == leader) base = atomicAdd(&cursor[ex], __popcll(m));
                base = __shfl(base, leader);
                if (e == ex) pos = base + __popcll(m & ((1ull << lane) - 1ull));
            }
        }
        pairTok[pos] = t;
        pairW[pos] = tokW[2 * t + k];
        invMap[2 * t + k] = pos;
    }
}

// ---------------- conversions ----------------
__global__ void k_cvt_x(const float* __restrict__ src, unsigned short* __restrict__ dst) {
    size_t i4 = ((size_t)blockIdx.x * 256 + threadIdx.x) * 4;
    float4 v = *(const float4*)(src + i4);
    ushort4 o;
    o.x = f2bf(v.x); o.y = f2bf(v.y); o.z = f2bf(v.z); o.w = f2bf(v.w);
    *(ushort4*)(dst + i4) = o;
}

__global__ void k_cvt_w(const float* __restrict__ src, unsigned short* __restrict__ dst,
                        const float* __restrict__ scale, int shift) {
    size_t i4 = ((size_t)blockIdx.x * 256 + threadIdx.x) * 4;
    float s = scale[i4 >> shift];
    float4 v = *(const float4*)(src + i4);
    ushort4 o;
    o.x = f2bf(v.x * s); o.y = f2bf(v.y * s); o.z = f2bf(v.z * s); o.w = f2bf(v.w * s);
    *(ushort4*)(dst + i4) = o;
}

// stage one half-tile (2 x global_load_lds, 8KB x 8 waves = 16KB)
#define STG_A2(buf, jlo, k0)                                                  \
    do { gl_lds16(aSrc[jlo] + (k0) + lcs, &lA[buf][aoff[jlo]]);               \
         gl_lds16(aSrc[(jlo)+1] + (k0) + lcs, &lA[buf][aoff[(jlo)+1]]); } while (0)
#define STG_B2(buf, jlo, k0)                                                  \
    do { gl_lds16(bSrc[jlo] + (k0) + lcs, &lB[buf][boff[jlo]]);               \
         gl_lds16(bSrc[(jlo)+1] + (k0) + lcs, &lB[buf][boff[(jlo)+1]]); } while (0)

#define PHASE_SYNC_MFMA(BVEC, C0, C1)                                         \
    __builtin_amdgcn_s_barrier();                                             \
    asm volatile("s_waitcnt lgkmcnt(0)" ::: "memory");                        \
    __builtin_amdgcn_sched_barrier(0);                                        \
    __builtin_amdgcn_s_setprio(1);                                            \
    mfma8(a, BVEC, C0, C1);                                                   \
    __builtin_amdgcn_s_setprio(0);                                            \
    __builtin_amdgcn_s_barrier();

// One K-tile = 4 quadrant phases. Staging schedule (1 half-tile/phase, m201):
//   p0: A-h1(T+1) -> nxt   (nxt's A-h1 was last read at tile T-1 p2: done)
//   p1: B-n0(T+2) -> cur   (cur B-n0 read at p0: done)
//   p2: B-n1(T+2) -> cur   (cur B-n1 read at p1: done)
//   p3: A-h0(T+2) -> cur   (cur A-h0 read at p0: done), then vmcnt(6):
//       leaves exactly T+2's 3 staged halves (6 loads) in flight and forces
//       everything older (incl. all of tile T+1) landed.
#define TILE_BODY(cur, Tv, DOA1, DOT2)                                        \
    do {                                                                      \
        const unsigned short* lAc = lA[cur];                                  \
        const unsigned short* lBc = lB[cur];                                  \
        /* p0: q(a0,b0) */                                                    \
        rd_a(lAc, wm * 128, lane, a);                                         \
        rd_b(lBc, bbase, lane, b0);                                           \
        if (DOA1) STG_A2((cur) ^ 1, 2, ((Tv) + 1) * BK);                      \
        asm volatile("s_waitcnt lgkmcnt(8)" ::: "memory");                    \
        PHASE_SYNC_MFMA(b0, &acc[0][0], &acc[1][0])                           \
        /* p1: q(a0,b1) */                                                    \
        rd_b(lBc, bbase + 32, lane, b1);                                      \
        if (DOT2) STG_B2(cur, 0, ((Tv) + 2) * BK);                            \
        PHASE_SYNC_MFMA(b1, &acc[0][1], &acc[1][1])                           \
        /* p2: q(a1,b0) */                                                    \
        rd_a(lAc, wm * 128 + 64, lane, a);                                    \
        if (DOT2) STG_B2(cur, 2, ((Tv) + 2) * BK);                            \
        PHASE_SYNC_MFMA(b0, &acc[2][0], &acc[3][0])                           \
        /* p3: q(a1,b1) */                                                    \
        if (DOT2) {                                                           \
            STG_A2(cur, 0, ((Tv) + 2) * BK);                                  \
            asm volatile("s_waitcnt vmcnt(6)" ::: "memory");                  \
        } else {                                                              \
            asm volatile("s_waitcnt vmcnt(0)" ::: "memory");                  \
        }                                                                     \
        __builtin_amdgcn_sched_barrier(0);                                    \
        __builtin_amdgcn_s_barrier();                                         \
        __builtin_amdgcn_s_setprio(1);                                        \
        mfma8(a, b1, &acc[2][1], &acc[3][1]);                                 \
        __builtin_amdgcn_s_setprio(0);                                        \
        __builtin_amdgcn_s_barrier();                                         \
    } while (0)

// prologue: tile0 fully + tile1 {Bn0,Bn1,Ah0} (7 halves, 14 loads);
// vmcnt(6) -> tile0's 8 loads landed, tile1's 6 in flight.
#define GEMM_PROLOGUE                                                         \
    STG_A2(0, 0, 0); STG_A2(0, 2, 0); STG_B2(0, 0, 0); STG_B2(0, 2, 0);       \
    STG_B2(1, 0, BK); STG_B2(1, 2, BK); STG_A2(1, 0, BK);                     \
    asm volatile("s_waitcnt vmcnt(6)" ::: "memory");                          \
    __builtin_amdgcn_sched_barrier(0);                                        \
    __builtin_amdgcn_s_barrier();

#define GEMM_MAINLOOP                                                         \
    GEMM_PROLOGUE                                                             \
    _Pragma("unroll 2")                                                       \
    for (int T = 0; T < KITER - 2; T++) TILE_BODY(T & 1, T, 1, 1);            \
    TILE_BODY(0, KITER - 2, 1, 0);   /* stage Ah1(15); drain vmcnt(0) */      \
    TILE_BODY(1, KITER - 1, 0, 0);   /* pure compute */

// ---------------- GEMM1: h = silu(x@Wg^T) * (x@Wu^T), gathered rows ----------------
// block 512 thr (8 waves, 2x4). tile: 256 rows x 128 h-cols x {gate,up}.
// B tile rows 0-127 = gate, 128-255 = up. Wave = 128 rows x 64 B-rows.
__global__ __launch_bounds__(512, 2)
void k_gemm1(const unsigned short* __restrict__ xbf,   // [T][H] bf16
             const unsigned short* __restrict__ w1bf,  // [E][2I][H] bf16 (dequant)
             const int* __restrict__ pairTok,
             const int* __restrict__ offsets, const int* __restrict__ tileOff,
             unsigned short* __restrict__ hbuf) {      // [NPAIR][I] bf16
    __shared__ unsigned short lA[2][BM * BK];          // 64 KB (double-buffered A)
    __shared__ unsigned short lB[2][BM * BK];          // 64 KB (double-buffered B)

    int mt = blockIdx.x;
    if (mt >= tileOff[E_NUM]) return;
    int e = 0;
    while (mt >= tileOff[e + 1]) e++;
    int row0 = offsets[e] + (mt - tileOff[e]) * BM;
    int valid = offsets[e + 1] - row0; if (valid > BM) valid = BM;

    int nt = blockIdx.y;                 // 0..7, 128 h-cols per block
    int tid = threadIdx.x;
    int lane = tid & 63, wave = tid >> 6;
    int wm = wave >> 2, wn = wave & 3;
    int lr = lane >> 3;
    int lcs = ((lane & 7) ^ lr) * 8;
    int bbase = (wn & 1) * 64 + (wn >> 1) * 128;   // wn0,1 = gate cols; wn2,3 = up

    const unsigned short* wg = w1bf + (size_t)e * 2 * I_DIM * H_DIM + (size_t)(nt * 128) * H_DIM;
    const unsigned short* wu = wg + (size_t)I_DIM * H_DIM;

    const unsigned short* aSrc[4];
    const unsigned short* bSrc[4];
    int aoff[4], boff[4];
#pragma unroll
    for (int j = 0; j < 4; j++) {
        int ab = blkA_of(wave, j), bb = blkB_of(wave, j);
        aoff[j] = ab * 512; boff[j] = bb * 512;
        int ra = ab * 8 + lr;
        int rc = ra < valid ? ra : valid - 1;
        aSrc[j] = xbf + (size_t)pairTok[row0 + rc] * H_DIM;
        int rb = bb * 8 + lr;
        bSrc[j] = (rb < 128) ? (wg + (size_t)rb * H_DIM) : (wu + (size_t)(rb - 128) * H_DIM);
    }

    v16f acc[4][2];
#pragma unroll
    for (int i = 0; i < 4; i++) { acc[i][0] = (v16f)0.f; acc[i][1] = (v16f)0.f; }

    v8s a[2][4], b0[4], b1[4];
    GEMM_MAINLOOP

    // epilogue: up-waves deposit u into uLds[256][128]; gate-waves fuse silu(g)*u
    __syncthreads();
    unsigned short* uLds = &lA[0][0];    // 64 KB = [256][128] bf16
    int half = lane >> 5, c = lane & 31;
    if (wn >= 2) {
#pragma unroll
        for (int i = 0; i < 4; i++)
#pragma unroll
            for (int r = 0; r < 16; r++) {
                int row = wm * 128 + i * 32 + (r & 3) + 8 * (r >> 2) + 4 * half;
#pragma unroll
                for (int j = 0; j < 2; j++)
                    uLds[row * 128 + (wn - 2) * 64 + j * 32 + c] = f2bf(acc[i][j][r]);
            }
    }
    __syncthreads();
    if (wn < 2) {
#pragma unroll
        for (int i = 0; i < 4; i++)
#pragma unroll
            for (int r = 0; r < 16; r++) {
                int row = wm * 128 + i * 32 + (r & 3) + 8 * (r >> 2) + 4 * half;
                if (row < valid) {
                    size_t base = (size_t)(row0 + row) * I_DIM + nt * 128;
#pragma unroll
                    for (int j = 0; j < 2; j++) {
                        float g = acc[i][j][r];
                        float uu = bf2f(uLds[row * 128 + wn * 64 + j * 32 + c]);
                        float s = g / (1.f + __expf(-g));
                        hbuf[base + wn * 64 + j * 32 + c] = f2bf(s * uu);
                    }
                }
            }
    }
}

// ---------------- GEMM2: ybuf[pos] = coef * (h[pos] @ W2^T), bf16 ----------------
// block 512 thr (8 waves, 2x4). tile: 256 rows x 256 out-cols. Wave 128x64.
__global__ __launch_bounds__(512, 2)
void k_gemm2(const unsigned short* __restrict__ hbuf,  // [NPAIR][I]
             const unsigned short* __restrict__ w2bf,  // [E][H][I] bf16 (dequant)
             const float* __restrict__ pairW,
             const int* __restrict__ offsets, const int* __restrict__ tileOff,
             unsigned short* __restrict__ ybuf) {      // [NPAIR][H] bf16
    __shared__ unsigned short lA[2][BM * BK];          // 64 KB
    __shared__ unsigned short lB[2][BM * BK];          // 64 KB

    int mt = blockIdx.x;
    if (mt >= tileOff[E_NUM]) return;
    int e = 0;
    while (mt >= tileOff[e + 1]) e++;
    int row0 = offsets[e] + (mt - tileOff[e]) * BM;
    int valid = offsets[e + 1] - row0; if (valid > BM) valid = BM;

    int nt = blockIdx.y;                 // 0..3, 256 out-cols per block
    int tid = threadIdx.x;
    int lane = tid & 63, wave = tid >> 6;
    int wm = wave >> 2, wn = wave & 3;
    int lr = lane >> 3;
    int lcs = ((lane & 7) ^ lr) * 8;
    int bbase = wn * 64;

    const unsigned short* w2e = w2bf + (size_t)e * H_DIM * I_DIM + (size_t)(nt * 256) * I_DIM;

    const unsigned short* aSrc[4];
    const unsigned short* bSrc[4];
    int aoff[4], boff[4];
#pragma unroll
    for (int j = 0; j < 4; j++) {
        int ab = blkA_of(wave, j), bb = blkB_of(wave, j);
        aoff[j] = ab * 512; boff[j] = bb * 512;
        int ra = ab * 8 + lr;
        int rc = ra < valid ? ra : valid - 1;
        aSrc[j] = hbuf + (size_t)(row0 + rc) * I_DIM;
        bSrc[j] = w2e + (size_t)(bb * 8 + lr) * I_DIM;
    }

    v16f acc[4][2];
#pragma unroll
    for (int i = 0; i < 4; i++) { acc[i][0] = (v16f)0.f; acc[i][1] = (v16f)0.f; }

    v8s a[2][4], b0[4], b1[4];
    GEMM_MAINLOOP

    int half = lane >> 5, c = lane & 31;
#pragma unroll
    for (int i = 0; i < 4; i++)
#pragma unroll
        for (int r = 0; r < 16; r++) {
            int row = wm * 128 + i * 32 + (r & 3) + 8 * (r >> 2) + 4 * half;
            if (row < valid) {
                int pos = row0 + row;
                float coef = pairW[pos];
                unsigned short* orow = ybuf + (size_t)pos * H_DIM + nt * 256;
#pragma unroll
                for (int j = 0; j < 2; j++)
                    orow[bbase + j * 32 + c] = f2bf(coef * acc[i][j][r]);
            }
        }
}

// ---------------- reduce: out[t] = ybuf[pair0(t)] + ybuf[pair1(t)] ----------------
__global__ __launch_bounds__(256)
void k_reduce(const unsigned short* __restrict__ ybuf,
              const int* __restrict__ invMap,
              float* __restrict__ out) {
    int t = blockIdx.x;
    int p0 = invMap[2 * t], p1 = invMap[2 * t + 1];
    int c4 = threadIdx.x * 4;
    ushort4 a = *(const ushort4*)(ybuf + (size_t)p0 * H_DIM + c4);
    ushort4 b = *(const ushort4*)(ybuf + (size_t)p1 * H_DIM + c4);
    float4 o;
    o.x = bf2f(a.x) + bf2f(b.x);
    o.y = bf2f(a.y) + bf2f(b.y);
    o.z = bf2f(a.z) + bf2f(b.z);
    o.w = bf2f(a.w) + bf2f(b.w);
    *(float4*)(out + (size_t)t * H_DIM + c4) = o;
}

extern "C" void kernel_launch(void* const* d_in, const int* in_sizes, int n_in,
                              void* d_out, int out_size, void* d_ws, size_t ws_size,
                              hipStream_t stream) {
    const float* x      = (const float*)d_in[0];
    const float* gating = (const float*)d_in[1];
    const float* w1     = (const float*)d_in[2];
    const float* w2     = (const float*)d_in[3];
    const float* w1s    = (const float*)d_in[4];
    const float* w2s    = (const float*)d_in[5];
    float* out = (float*)d_out;

    char* ws = (char*)d_ws;
    size_t off = 0;
    auto alloc = [&](size_t bytes) { void* p = ws + off; off += (bytes + 255) & ~(size_t)255; return p; };
    unsigned short* xbf  = (unsigned short*)alloc((size_t)T_TOK * H_DIM * 2);             // 32 MB
    unsigned short* w1bf = (unsigned short*)alloc((size_t)E_NUM * 2 * I_DIM * H_DIM * 2); // 32 MB
    unsigned short* w2bf = (unsigned short*)alloc((size_t)E_NUM * H_DIM * I_DIM * 2);     // 16 MB
    unsigned short* hbuf = (unsigned short*)alloc((size_t)NPAIR * I_DIM * 2);             // 64 MB
    unsigned short* ybuf = (unsigned short*)alloc((size_t)NPAIR * H_DIM * 2);             // 64 MB
    int*   pairTok  = (int*)alloc(NPAIR * 4);
    float* pairW    = (float*)alloc(NPAIR * 4);
    int*   tokExp   = (int*)alloc(NPAIR * 4);
    float* tokW     = (float*)alloc(NPAIR * 4);
    int*   invMap   = (int*)alloc(NPAIR * 4);
    int*   counts   = (int*)alloc(64);
    int*   offsets  = (int*)alloc(64);
    int*   tileOff  = (int*)alloc(64);
    int*   cursor   = (int*)alloc(64);

    hipMemsetAsync(counts, 0, 64, stream);

    k_route<<<T_TOK / 256, 256, 0, stream>>>(gating, tokExp, tokW, counts);
    k_scan<<<1, 64, 0, stream>>>(counts, offsets, tileOff, cursor);
    k_scatter<<<T_TOK / 256, 256, 0, stream>>>(tokExp, tokW, cursor, pairTok, pairW, invMap);
    k_cvt_x<<<(T_TOK * H_DIM / 4) / 256, 256, 0, stream>>>(x, xbf);
    k_cvt_w<<<(E_NUM * 2 * I_DIM * H_DIM / 4) / 256, 256, 0, stream>>>(w1, w1bf, w1s, 21);
    k_cvt_w<<<(E_NUM * H_DIM * I_DIM / 4) / 256, 256, 0, stream>>>(w2, w2bf, w2s, 20);

    dim3 g1(MAX_MT, I_DIM / 128);         // 136 x 8
    k_gemm1<<<g1, 512, 0, stream>>>(xbf, w1bf, pairTok, offsets, tileOff, hbuf);
    dim3 g2(MAX_MT, H_DIM / 256);         // 136 x 4
    k_gemm2<<<g2, 512, 0, stream>>>(hbuf, w2bf, pairW, offsets, tileOff, ybuf);
    k_reduce<<<T_TOK, 256, 0, stream>>>(ybuf, invMap, out);
}

// Round 3
// 650.281 us; speedup vs baseline: 1.0146x; 1.0146x over previous
//
#include <hip/hip_runtime.h>
#include <hip/hip_bf16.h>

#define T_TOK 16384
#define H_DIM 1024
#define I_DIM 1024
#define E_NUM 8
#define NPAIR (T_TOK * 2)
#define BM 128
#define BK 64
#define MAX_MT (NPAIR / BM + E_NUM)     // 264 worst-case 128-row tiles

typedef float v4f __attribute__((ext_vector_type(4)));
typedef float v16f __attribute__((ext_vector_type(16)));
typedef short v8s __attribute__((ext_vector_type(8)));

__device__ __forceinline__ unsigned short f2bf(float f) {
    unsigned int u = __float_as_uint(f);
    unsigned int r = (u + 0x7fffu + ((u >> 16) & 1u)) >> 16;   // RNE
    return (unsigned short)r;
}
__device__ __forceinline__ float bf2f(unsigned short s) {
    return __uint_as_float(((unsigned int)s) << 16);
}

__device__ __forceinline__ void gl_lds16(const void* g, void* l) {
    __builtin_amdgcn_global_load_lds(
        (const __attribute__((address_space(1))) void*)g,
        (__attribute__((address_space(3))) void*)l, 16, 0, 0);
}

// XOR-swizzled LDS tile: row-major [rows][64 bf16], each row's eight 16B units
// xor'd by (row&7). Staged by swizzling the GLOBAL source column per lane.
__device__ __forceinline__ int swz(int row, int unit) {
    return row * 64 + ((unit ^ (row & 7)) << 3);
}

// ---------------- routing ----------------
__global__ void k_route(const float* __restrict__ gating,
                        int* __restrict__ tokExp, float* __restrict__ tokW,
                        int* __restrict__ counts) {
    int t = blockIdx.x * 256 + threadIdx.x;
    int lane = threadIdx.x & 63;
    float g[E_NUM];
#pragma unroll
    for (int e = 0; e < E_NUM; e++) g[e] = gating[t * E_NUM + e];
    int i0 = 0; float v0 = g[0];
#pragma unroll
    for (int e = 1; e < E_NUM; e++) if (g[e] > v0) { v0 = g[e]; i0 = e; }
    int i1 = -1; float v1 = -1e30f;
#pragma unroll
    for (int e = 0; e < E_NUM; e++) if (e != i0 && g[e] > v1) { v1 = g[e]; i1 = e; }
    float w0 = 1.f / (1.f + __expf(v1 - v0));   // renormalized top-2
    tokExp[2 * t] = i0; tokExp[2 * t + 1] = i1;
    tokW[2 * t] = w0;   tokW[2 * t + 1] = 1.f - w0;
#pragma unroll
    for (int e = 0; e < E_NUM; e++) {
        unsigned long long mA = __ballot(i0 == e);
        unsigned long long mB = __ballot(i1 == e);
        int c = __popcll(mA) + __popcll(mB);
        if (lane == 0 && c) atomicAdd(&counts[e], c);
    }
}

__global__ void k_scan(const int* __restrict__ counts, int* __restrict__ offsets,
                       int* __restrict__ tileOff, int* __restrict__ cursor) {
    if (threadIdx.x == 0 && blockIdx.x == 0) {
        int o = 0, to = 0;
        for (int e = 0; e < E_NUM; e++) {
            offsets[e] = o; tileOff[e] = to; cursor[e] = o;
            o += counts[e];
            to += (counts[e] + BM - 1) / BM;
        }
        offsets[E_NUM] = o; tileOff[E_NUM] = to;
    }
}

__global__ void k_scatter(const int* __restrict__ tokExp, const float* __restrict__ tokW,
                          int* __restrict__ cursor,
                          int* __restrict__ pairTok, float* __restrict__ pairW) {
    int t = blockIdx.x * 256 + threadIdx.x;
    int lane = threadIdx.x & 63;
#pragma unroll
    for (int k = 0; k < 2; k++) {
        int e = tokExp[2 * t + k];
        int pos = 0;
#pragma unroll
        for (int ex = 0; ex < E_NUM; ex++) {
            unsigned long long m = __ballot(e == ex);
            if (m) {
                int leader = __builtin_ctzll(m);
                int base = 0;
                if (lane == leader) base = atomicAdd(&cursor[ex], __popcll(m));
                base = __shfl(base, leader);
                if (e == ex) pos = base + __popcll(m & ((1ull << lane) - 1ull));
            }
        }
        pairTok[pos] = t;
        pairW[pos] = tokW[2 * t + k];
    }
}

// ---------------- fused conversions: x, w1 (scaled), w2 (scaled) -> bf16 --------
__global__ void k_cvt_all(const float* __restrict__ x,
                          const float* __restrict__ w1, const float* __restrict__ w2,
                          const float* __restrict__ w1s, const float* __restrict__ w2s,
                          unsigned short* __restrict__ xbf,
                          unsigned short* __restrict__ w1bf,
                          unsigned short* __restrict__ w2bf) {
    const size_t N0 = (size_t)T_TOK * H_DIM;               // 16.78M
    const size_t N1 = (size_t)E_NUM * 2 * I_DIM * H_DIM;   // 16.78M
    size_t i4 = ((size_t)blockIdx.x * 256 + threadIdx.x) * 4;
    const float* src; unsigned short* dst; size_t off; float s;
    if (i4 < N0)            { src = x;  dst = xbf;  off = i4;           s = 1.f; }
    else if (i4 < N0 + N1)  { src = w1; dst = w1bf; off = i4 - N0;      s = w1s[off >> 21]; }
    else                    { src = w2; dst = w2bf; off = i4 - N0 - N1; s = w2s[off >> 20]; }
    float4 v = *(const float4*)(src + off);
    ushort4 o;
    o.x = f2bf(v.x * s); o.y = f2bf(v.y * s); o.z = f2bf(v.z * s); o.w = f2bf(v.w * s);
    *(ushort4*)(dst + off) = o;
}

// ---------------- GEMM1: h = silu(x@Wg^T) * (x@Wu^T), gathered rows ----------------
// block 512 thr (8 waves). tile: 128 rows x 128 h-cols x {gate,up}. K=1024.
// waves 0-3 gate, 4-7 up; each wave 64x64, acc 2x2x16 = 64 regs.
// Epilogue: up-waves deposit u into lB; gate-waves fuse silu(g)*u.
// Epilogue LDS col-block is XOR'd by (row&4)<<3 so the two lane-halves
// (rows r, r+4) land in disjoint 16-bank groups (was a 4-way conflict).
__global__ __launch_bounds__(512, 4)
void k_gemm1(const unsigned short* __restrict__ xbf,   // [T][H] bf16
             const unsigned short* __restrict__ w1bf,  // [E][2I][H] bf16 (dequant)
             const int* __restrict__ pairTok,
             const int* __restrict__ offsets, const int* __restrict__ tileOff,
             unsigned short* __restrict__ hbuf) {      // [NPAIR][I] bf16
    __shared__ unsigned short lA[BM * BK];             // 16 KB
    __shared__ unsigned short lB[256 * BK];            // 32 KB: rows 0-127 gate, 128-255 up

    int mt = blockIdx.x;
    if (mt >= tileOff[E_NUM]) return;
    int e = 0;
    while (mt >= tileOff[e + 1]) e++;
    int row0 = offsets[e] + (mt - tileOff[e]) * BM;
    int valid = offsets[e + 1] - row0; if (valid > BM) valid = BM;

    int nt = blockIdx.y;                 // 0..7, 128 h-cols per block
    int tid = threadIdx.x;
    int lane = tid & 63, wave = tid >> 6;      // wave 0..7
    int role = wave >> 2, quad = wave & 3;     // role 0 = gate, 1 = up
    int wm = quad >> 1, wn = quad & 1;

    int lr = lane >> 3;
    int lcs = ((lane & 7) ^ lr) * 8;     // swizzled global col (bf16 units)

    const unsigned short* wg = w1bf + (size_t)e * 2 * I_DIM * H_DIM + (size_t)(nt * 128) * H_DIM;
    const unsigned short* wu = wg + (size_t)I_DIM * H_DIM;

    int tokRow[2];
#pragma unroll
    for (int j = 0; j < 2; j++) {
        int r = wave * 16 + j * 8 + lr;
        int rc = r < valid ? r : valid - 1;
        tokRow[j] = pairTok[row0 + rc];
    }
    const unsigned short* bRow[4];
#pragma unroll
    for (int j = 0; j < 4; j++) {
        int brow = wave * 32 + j * 8 + lr;     // 0..255
        bRow[j] = (brow < 128) ? (wg + (size_t)brow * H_DIM)
                               : (wu + (size_t)(brow - 128) * H_DIM);
    }

    v16f acc[2][2];
#pragma unroll
    for (int i = 0; i < 2; i++)
#pragma unroll
        for (int j = 0; j < 2; j++) acc[i][j] = (v16f)0.f;

    for (int ko = 0; ko < H_DIM / BK; ko++) {
        int k0 = ko * BK;
        __syncthreads();
#pragma unroll
        for (int j = 0; j < 2; j++)      // A: 2 chunks/wave = 128 rows total
            gl_lds16(xbf + (size_t)tokRow[j] * H_DIM + k0 + lcs, lA + (wave * 2 + j) * 512);
#pragma unroll
        for (int j = 0; j < 4; j++)      // B: 4 chunks/wave = 256 rows total
            gl_lds16(bRow[j] + k0 + lcs, lB + (wave * 4 + j) * 512);
        __syncthreads();
#pragma unroll
        for (int kk = 0; kk < BK; kk += 16) {
            int u = (kk >> 3) + (lane >> 5);
            v8s a[2], b[2];
#pragma unroll
            for (int i = 0; i < 2; i++)
                a[i] = *(const v8s*)(lA + swz(wm * 64 + i * 32 + (lane & 31), u));
#pragma unroll
            for (int j = 0; j < 2; j++)
                b[j] = *(const v8s*)(lB + swz(role * 128 + wn * 64 + j * 32 + (lane & 31), u));
#pragma unroll
            for (int i = 0; i < 2; i++)
#pragma unroll
                for (int j = 0; j < 2; j++)
                    acc[i][j] = __builtin_amdgcn_mfma_f32_32x32x16_bf16(a[i], b[j], acc[i][j], 0, 0, 0);
        }
    }

    int half = lane >> 5, c = lane & 31;
    __syncthreads();
    if (role == 1) {                     // up-waves: deposit u into lB as [128][128] bf16
#pragma unroll
        for (int i = 0; i < 2; i++)
#pragma unroll
            for (int r = 0; r < 16; r++) {
                int row = wm * 64 + i * 32 + (r & 3) + 8 * (r >> 2) + 4 * half;
#pragma unroll
                for (int j = 0; j < 2; j++) {
                    int cs = (j * 32 + c) ^ ((row & 4) << 3);   // bank-conflict fix
                    lB[row * 128 + wn * 64 + cs] = f2bf(acc[i][j][r]);
                }
            }
    }
    __syncthreads();
    if (role == 0) {                     // gate-waves: silu(g) * u -> hbuf
#pragma unroll
        for (int i = 0; i < 2; i++)
#pragma unroll
            for (int r = 0; r < 16; r++) {
                int row = wm * 64 + i * 32 + (r & 3) + 8 * (r >> 2) + 4 * half;
                if (row < valid) {
                    size_t base = (size_t)(row0 + row) * I_DIM + nt * 128;
#pragma unroll
                    for (int j = 0; j < 2; j++) {
                        float g = acc[i][j][r];
                        int cs = (j * 32 + c) ^ ((row & 4) << 3);   // same mapping
                        float uu = bf2f(lB[row * 128 + wn * 64 + cs]);
                        float s = g / (1.f + __expf(-g));
                        hbuf[base + wn * 64 + j * 32 + c] = f2bf(s * uu);
                    }
                }
            }
    }
}

// ---------------- GEMM2: out[tok] += coef * (h[pos] @ W2^T), f32 atomics --------
// block 512 thr (8 waves, 2x4). tile: 128 rows x 256 out-cols. wave 64x64, acc 64.
__global__ __launch_bounds__(512, 4)
void k_gemm2(const unsigned short* __restrict__ hbuf,  // [NPAIR][I]
             const unsigned short* __restrict__ w2bf,  // [E][H][I] bf16 (dequant)
             const float* __restrict__ pairW, const int* __restrict__ pairTok,
             const int* __restrict__ offsets, const int* __restrict__ tileOff,
             float* __restrict__ out) {                // [T][H] f32 (pre-zeroed)
    __shared__ unsigned short lA[BM * BK];             // 16 KB
    __shared__ unsigned short lB[256 * BK];            // 32 KB

    int mt = blockIdx.x;
    if (mt >= tileOff[E_NUM]) return;
    int e = 0;
    while (mt >= tileOff[e + 1]) e++;
    int row0 = offsets[e] + (mt - tileOff[e]) * BM;
    int valid = offsets[e + 1] - row0; if (valid > BM) valid = BM;

    int nt = blockIdx.y;                 // 0..3, 256 out-cols per block
    int tid = threadIdx.x;
    int lane = tid & 63, wave = tid >> 6;
    int wm = wave >> 2, wn = wave & 3;   // 2 x 4 wave grid

    int lr = lane >> 3;
    int lcs = ((lane & 7) ^ lr) * 8;

    const unsigned short* w2e = w2bf + (size_t)e * H_DIM * I_DIM + (size_t)(nt * 256) * I_DIM;

    int rowA[2];
#pragma unroll
    for (int j = 0; j < 2; j++) {
        int r = wave * 16 + j * 8 + lr;
        int rc = r < valid ? r : valid - 1;
        rowA[j] = row0 + rc;
    }

    v16f acc[2][2];
#pragma unroll
    for (int i = 0; i < 2; i++)
#pragma unroll
        for (int j = 0; j < 2; j++) acc[i][j] = (v16f)0.f;

    for (int ko = 0; ko < I_DIM / BK; ko++) {
        int k0 = ko * BK;
        __syncthreads();
#pragma unroll
        for (int j = 0; j < 2; j++)      // A: 2 chunks/wave = 128 rows
            gl_lds16(hbuf + (size_t)rowA[j] * I_DIM + k0 + lcs, lA + (wave * 2 + j) * 512);
#pragma unroll
        for (int j = 0; j < 4; j++)      // B: 4 chunks/wave = 256 rows
            gl_lds16(w2e + (size_t)(wave * 32 + j * 8 + lr) * I_DIM + k0 + lcs,
                     lB + (wave * 4 + j) * 512);
        __syncthreads();
#pragma unroll
        for (int kk = 0; kk < BK; kk += 16) {
            int u = (kk >> 3) + (lane >> 5);
            v8s a[2], b[2];
#pragma unroll
            for (int i = 0; i < 2; i++)
                a[i] = *(const v8s*)(lA + swz(wm * 64 + i * 32 + (lane & 31), u));
#pragma unroll
            for (int j = 0; j < 2; j++)
                b[j] = *(const v8s*)(lB + swz(wn * 64 + j * 32 + (lane & 31), u));
#pragma unroll
            for (int i = 0; i < 2; i++)
#pragma unroll
                for (int j = 0; j < 2; j++)
                    acc[i][j] = __builtin_amdgcn_mfma_f32_32x32x16_bf16(a[i], b[j], acc[i][j], 0, 0, 0);
        }
    }

    int half = lane >> 5, c = lane & 31;
#pragma unroll
    for (int i = 0; i < 2; i++)
#pragma unroll
        for (int r = 0; r < 16; r++) {
            int row = wm * 64 + i * 32 + (r & 3) + 8 * (r >> 2) + 4 * half;
            if (row < valid) {
                int pos = row0 + row;
                float coef = pairW[pos];
                int tok = pairTok[pos];
                float* orow = out + (size_t)tok * H_DIM + nt * 256;
#pragma unroll
                for (int j = 0; j < 2; j++)
                    atomicAdd(&orow[wn * 64 + j * 32 + c], coef * acc[i][j][r]);
            }
        }
}

extern "C" void kernel_launch(void* const* d_in, const int* in_sizes, int n_in,
                              void* d_out, int out_size, void* d_ws, size_t ws_size,
                              hipStream_t stream) {
    const float* x      = (const float*)d_in[0];
    const float* gating = (const float*)d_in[1];
    const float* w1     = (const float*)d_in[2];
    const float* w2     = (const float*)d_in[3];
    const float* w1s    = (const float*)d_in[4];
    const float* w2s    = (const float*)d_in[5];
    float* out = (float*)d_out;

    char* ws = (char*)d_ws;
    size_t off = 0;
    auto alloc = [&](size_t bytes) { void* p = ws + off; off += (bytes + 255) & ~(size_t)255; return p; };
    unsigned short* xbf  = (unsigned short*)alloc((size_t)T_TOK * H_DIM * 2);             // 32 MB
    unsigned short* w1bf = (unsigned short*)alloc((size_t)E_NUM * 2 * I_DIM * H_DIM * 2); // 32 MB
    unsigned short* w2bf = (unsigned short*)alloc((size_t)E_NUM * H_DIM * I_DIM * 2);     // 16 MB
    unsigned short* hbuf = (unsigned short*)alloc((size_t)NPAIR * I_DIM * 2);             // 64 MB
    int*   pairTok  = (int*)alloc(NPAIR * 4);
    float* pairW    = (float*)alloc(NPAIR * 4);
    int*   tokExp   = (int*)alloc(NPAIR * 4);
    float* tokW     = (float*)alloc(NPAIR * 4);
    int*   counts   = (int*)alloc(64);
    int*   offsets  = (int*)alloc(64);
    int*   tileOff  = (int*)alloc(64);
    int*   cursor   = (int*)alloc(64);

    hipMemsetAsync(counts, 0, 64, stream);
    hipMemsetAsync(out, 0, (size_t)T_TOK * H_DIM * 4, stream);   // for gemm2 atomics

    k_route<<<T_TOK / 256, 256, 0, stream>>>(gating, tokExp, tokW, counts);
    k_scan<<<1, 64, 0, stream>>>(counts, offsets, tileOff, cursor);
    k_scatter<<<T_TOK / 256, 256, 0, stream>>>(tokExp, tokW, cursor, pairTok, pairW);

    size_t ncvt = ((size_t)T_TOK * H_DIM + (size_t)E_NUM * 2 * I_DIM * H_DIM +
                   (size_t)E_NUM * H_DIM * I_DIM) / 4 / 256;     // 40960 blocks
    k_cvt_all<<<(int)ncvt, 256, 0, stream>>>(x, w1, w2, w1s, w2s, xbf, w1bf, w2bf);

    dim3 g1(MAX_MT, I_DIM / 128);         // 264 x 8
    k_gemm1<<<g1, 512, 0, stream>>>(xbf, w1bf, pairTok, offsets, tileOff, hbuf);
    dim3 g2(MAX_MT, H_DIM / 256);         // 264 x 4
    k_gemm2<<<g2, 512, 0, stream>>>(hbuf, w2bf, pairW, pairTok, offsets, tileOff, out);
}

// Round 4
// 581.191 us; speedup vs baseline: 1.1352x; 1.1189x over previous
//
#include <hip/hip_runtime.h>
#include <hip/hip_bf16.h>

#define T_TOK 16384
#define H_DIM 1024
#define I_DIM 1024
#define E_NUM 8
#define NPAIR (T_TOK * 2)
#define BM 128
#define BK 64
#define MAX_MT (NPAIR / BM + E_NUM)     // 264 worst-case 128-row tiles

typedef float v4f __attribute__((ext_vector_type(4)));
typedef float v16f __attribute__((ext_vector_type(16)));
typedef short v8s __attribute__((ext_vector_type(8)));

__device__ __forceinline__ unsigned short f2bf(float f) {
    unsigned int u = __float_as_uint(f);
    unsigned int r = (u + 0x7fffu + ((u >> 16) & 1u)) >> 16;   // RNE
    return (unsigned short)r;
}
__device__ __forceinline__ float bf2f(unsigned short s) {
    return __uint_as_float(((unsigned int)s) << 16);
}

__device__ __forceinline__ void gl_lds16(const void* g, void* l) {
    __builtin_amdgcn_global_load_lds(
        (const __attribute__((address_space(1))) void*)g,
        (__attribute__((address_space(3))) void*)l, 16, 0, 0);
}

// XOR-swizzled LDS tile: row-major [rows][64 bf16], each row's eight 16B units
// xor'd by (row&7). Staged by swizzling the GLOBAL source column per lane.
__device__ __forceinline__ int swz(int row, int unit) {
    return row * 64 + ((unit ^ (row & 7)) << 3);
}

// ---------------- routing ----------------
__global__ void k_route(const float* __restrict__ gating,
                        int* __restrict__ tokExp, float* __restrict__ tokW,
                        int* __restrict__ counts) {
    int t = blockIdx.x * 256 + threadIdx.x;
    int lane = threadIdx.x & 63;
    float g[E_NUM];
#pragma unroll
    for (int e = 0; e < E_NUM; e++) g[e] = gating[t * E_NUM + e];
    int i0 = 0; float v0 = g[0];
#pragma unroll
    for (int e = 1; e < E_NUM; e++) if (g[e] > v0) { v0 = g[e]; i0 = e; }
    int i1 = -1; float v1 = -1e30f;
#pragma unroll
    for (int e = 0; e < E_NUM; e++) if (e != i0 && g[e] > v1) { v1 = g[e]; i1 = e; }
    float w0 = 1.f / (1.f + __expf(v1 - v0));   // renormalized top-2
    tokExp[2 * t] = i0; tokExp[2 * t + 1] = i1;
    tokW[2 * t] = w0;   tokW[2 * t + 1] = 1.f - w0;
#pragma unroll
    for (int e = 0; e < E_NUM; e++) {
        unsigned long long mA = __ballot(i0 == e);
        unsigned long long mB = __ballot(i1 == e);
        int c = __popcll(mA) + __popcll(mB);
        if (lane == 0 && c) atomicAdd(&counts[e], c);
    }
}

__global__ void k_scan(const int* __restrict__ counts, int* __restrict__ offsets,
                       int* __restrict__ tileOff, int* __restrict__ cursor) {
    if (threadIdx.x == 0 && blockIdx.x == 0) {
        int o = 0, to = 0;
        for (int e = 0; e < E_NUM; e++) {
            offsets[e] = o; tileOff[e] = to; cursor[e] = o;
            o += counts[e];
            to += (counts[e] + BM - 1) / BM;
        }
        offsets[E_NUM] = o; tileOff[E_NUM] = to;
    }
}

__global__ void k_scatter(const int* __restrict__ tokExp, const float* __restrict__ tokW,
                          int* __restrict__ cursor,
                          int* __restrict__ pairTok, float* __restrict__ pairW,
                          int* __restrict__ invMap) {
    int t = blockIdx.x * 256 + threadIdx.x;
    int lane = threadIdx.x & 63;
#pragma unroll
    for (int k = 0; k < 2; k++) {
        int e = tokExp[2 * t + k];
        int pos = 0;
#pragma unroll
        for (int ex = 0; ex < E_NUM; ex++) {
            unsigned long long m = __ballot(e == ex);
            if (m) {
                int leader = __builtin_ctzll(m);
                int base = 0;
                if (lane == leader) base = atomicAdd(&cursor[ex], __popcll(m));
                base = __shfl(base, leader);
                if (e == ex) pos = base + __popcll(m & ((1ull << lane) - 1ull));
            }
        }
        pairTok[pos] = t;
        pairW[pos] = tokW[2 * t + k];
        invMap[2 * t + k] = pos;
    }
}

// ---------------- fused conversions: x, w1 (scaled), w2 (scaled) -> bf16 --------
__global__ void k_cvt_all(const float* __restrict__ x,
                          const float* __restrict__ w1, const float* __restrict__ w2,
                          const float* __restrict__ w1s, const float* __restrict__ w2s,
                          unsigned short* __restrict__ xbf,
                          unsigned short* __restrict__ w1bf,
                          unsigned short* __restrict__ w2bf) {
    const size_t N0 = (size_t)T_TOK * H_DIM;               // 16.78M
    const size_t N1 = (size_t)E_NUM * 2 * I_DIM * H_DIM;   // 16.78M
    size_t i4 = ((size_t)blockIdx.x * 256 + threadIdx.x) * 4;
    const float* src; unsigned short* dst; size_t off; float s;
    if (i4 < N0)            { src = x;  dst = xbf;  off = i4;           s = 1.f; }
    else if (i4 < N0 + N1)  { src = w1; dst = w1bf; off = i4 - N0;      s = w1s[off >> 21]; }
    else                    { src = w2; dst = w2bf; off = i4 - N0 - N1; s = w2s[off >> 20]; }
    float4 v = *(const float4*)(src + off);
    ushort4 o;
    o.x = f2bf(v.x * s); o.y = f2bf(v.y * s); o.z = f2bf(v.z * s); o.w = f2bf(v.w * s);
    *(ushort4*)(dst + off) = o;
}

// ---------------- GEMM1: h = silu(x@Wg^T) * (x@Wu^T), gathered rows ----------------
// 256 thr (4 waves, 1/SIMD). tile: 128 rows x 128 h-cols x {gate,up}. K=1024.
// wave = 64 rows x 128 cols of its role (waves 0-1 gate, 2-3 up), acc 2x4 v16f.
// Rationale: 64x128 wave tile reads 6KB LDS per 8 MFMA (96 B/cyc/SIMD demand)
// vs 64x64's 128 B/cyc -- lifts the LDS-read-BW ceiling from ~50% to ~67% MFMA.
__global__ __launch_bounds__(256, 2)
void k_gemm1(const unsigned short* __restrict__ xbf,   // [T][H] bf16
             const unsigned short* __restrict__ w1bf,  // [E][2I][H] bf16 (dequant)
             const int* __restrict__ pairTok,
             const int* __restrict__ offsets, const int* __restrict__ tileOff,
             unsigned short* __restrict__ hbuf) {      // [NPAIR][I] bf16
    __shared__ unsigned short lA[BM * BK];             // 16 KB
    __shared__ unsigned short lB[256 * BK];            // 32 KB: rows 0-127 gate, 128-255 up

    int mt = blockIdx.x;
    if (mt >= tileOff[E_NUM]) return;
    int e = 0;
    while (mt >= tileOff[e + 1]) e++;
    int row0 = offsets[e] + (mt - tileOff[e]) * BM;
    int valid = offsets[e + 1] - row0; if (valid > BM) valid = BM;

    int nt = blockIdx.y;                 // 0..7, 128 h-cols per block
    int tid = threadIdx.x;
    int lane = tid & 63, wave = tid >> 6;      // wave 0..3
    int role = wave >> 1, wm = wave & 1;       // role 0 = gate, 1 = up; wm = M-half

    int lr = lane >> 3;
    int lcs = ((lane & 7) ^ lr) * 8;     // swizzled global col (bf16 units)

    const unsigned short* wg = w1bf + (size_t)e * 2 * I_DIM * H_DIM + (size_t)(nt * 128) * H_DIM;
    const unsigned short* wu = wg + (size_t)I_DIM * H_DIM;

    int tokRow[4];
#pragma unroll
    for (int j = 0; j < 4; j++) {
        int r = wave * 32 + j * 8 + lr;
        int rc = r < valid ? r : valid - 1;
        tokRow[j] = pairTok[row0 + rc];
    }
    const unsigned short* bRow[8];
#pragma unroll
    for (int j = 0; j < 8; j++) {
        int brow = wave * 64 + j * 8 + lr;     // 0..255
        bRow[j] = (brow < 128) ? (wg + (size_t)brow * H_DIM)
                               : (wu + (size_t)(brow - 128) * H_DIM);
    }

    v16f acc[2][4];
#pragma unroll
    for (int i = 0; i < 2; i++)
#pragma unroll
        for (int j = 0; j < 4; j++) acc[i][j] = (v16f)0.f;

    for (int ko = 0; ko < H_DIM / BK; ko++) {
        int k0 = ko * BK;
        __syncthreads();
#pragma unroll
        for (int j = 0; j < 4; j++)      // A: 4 chunks/wave = 128 rows total
            gl_lds16(xbf + (size_t)tokRow[j] * H_DIM + k0 + lcs, lA + (wave * 4 + j) * 512);
#pragma unroll
        for (int j = 0; j < 8; j++)      // B: 8 chunks/wave = 256 rows total
            gl_lds16(bRow[j] + k0 + lcs, lB + (wave * 8 + j) * 512);
        __syncthreads();
#pragma unroll
        for (int kk = 0; kk < BK; kk += 16) {
            int u = (kk >> 3) + (lane >> 5);
            v8s a[2], b[4];
#pragma unroll
            for (int i = 0; i < 2; i++)
                a[i] = *(const v8s*)(lA + swz(wm * 64 + i * 32 + (lane & 31), u));
#pragma unroll
            for (int j = 0; j < 4; j++)
                b[j] = *(const v8s*)(lB + swz(role * 128 + j * 32 + (lane & 31), u));
#pragma unroll
            for (int i = 0; i < 2; i++)
#pragma unroll
                for (int j = 0; j < 4; j++)
                    acc[i][j] = __builtin_amdgcn_mfma_f32_32x32x16_bf16(a[i], b[j], acc[i][j], 0, 0, 0);
        }
    }

    // epilogue: up-waves deposit u into lB as [128][128]; gate-waves fuse silu(g)*u.
    // col-block XOR'd by (row&4)<<3 so lane-halves (rows r, r+4) hit disjoint banks.
    int half = lane >> 5, c = lane & 31;
    __syncthreads();
    if (role == 1) {
#pragma unroll
        for (int i = 0; i < 2; i++)
#pragma unroll
            for (int r = 0; r < 16; r++) {
                int row = wm * 64 + i * 32 + (r & 3) + 8 * (r >> 2) + 4 * half;
#pragma unroll
                for (int j = 0; j < 4; j++) {
                    int cs = (j * 32 + c) ^ ((row & 4) << 3);
                    lB[row * 128 + cs] = f2bf(acc[i][j][r]);
                }
            }
    }
    __syncthreads();
    if (role == 0) {
#pragma unroll
        for (int i = 0; i < 2; i++)
#pragma unroll
            for (int r = 0; r < 16; r++) {
                int row = wm * 64 + i * 32 + (r & 3) + 8 * (r >> 2) + 4 * half;
                if (row < valid) {
                    size_t base = (size_t)(row0 + row) * I_DIM + nt * 128;
#pragma unroll
                    for (int j = 0; j < 4; j++) {
                        float g = acc[i][j][r];
                        int cs = (j * 32 + c) ^ ((row & 4) << 3);
                        float uu = bf2f(lB[row * 128 + cs]);
                        float s = g / (1.f + __expf(-g));
                        hbuf[base + j * 32 + c] = f2bf(s * uu);
                    }
                }
            }
    }
}

// ---------------- GEMM2: ybuf[pos] = coef * (h[pos] @ W2^T), bf16 ----------------
// (round-0 control: 512 thr, 8 waves 2x4, tile 128 x 256, wave 64x64, acc 2x2)
__global__ __launch_bounds__(512, 4)
void k_gemm2(const unsigned short* __restrict__ hbuf,  // [NPAIR][I]
             const unsigned short* __restrict__ w2bf,  // [E][H][I] bf16 (dequant)
             const float* __restrict__ pairW,
             const int* __restrict__ offsets, const int* __restrict__ tileOff,
             unsigned short* __restrict__ ybuf) {      // [NPAIR][H] bf16
    __shared__ unsigned short lA[BM * BK];             // 16 KB
    __shared__ unsigned short lB[256 * BK];            // 32 KB

    int mt = blockIdx.x;
    if (mt >= tileOff[E_NUM]) return;
    int e = 0;
    while (mt >= tileOff[e + 1]) e++;
    int row0 = offsets[e] + (mt - tileOff[e]) * BM;
    int valid = offsets[e + 1] - row0; if (valid > BM) valid = BM;

    int nt = blockIdx.y;                 // 0..3, 256 out-cols per block
    int tid = threadIdx.x;
    int lane = tid & 63, wave = tid >> 6;
    int wm = wave >> 2, wn = wave & 3;   // 2 x 4 wave grid

    int lr = lane >> 3;
    int lcs = ((lane & 7) ^ lr) * 8;

    const unsigned short* w2e = w2bf + (size_t)e * H_DIM * I_DIM + (size_t)(nt * 256) * I_DIM;

    int rowA[2];
#pragma unroll
    for (int j = 0; j < 2; j++) {
        int r = wave * 16 + j * 8 + lr;
        int rc = r < valid ? r : valid - 1;
        rowA[j] = row0 + rc;
    }

    v16f acc[2][2];
#pragma unroll
    for (int i = 0; i < 2; i++)
#pragma unroll
        for (int j = 0; j < 2; j++) acc[i][j] = (v16f)0.f;

    for (int ko = 0; ko < I_DIM / BK; ko++) {
        int k0 = ko * BK;
        __syncthreads();
#pragma unroll
        for (int j = 0; j < 2; j++)      // A: 2 chunks/wave = 128 rows
            gl_lds16(hbuf + (size_t)rowA[j] * I_DIM + k0 + lcs, lA + (wave * 2 + j) * 512);
#pragma unroll
        for (int j = 0; j < 4; j++)      // B: 4 chunks/wave = 256 rows
            gl_lds16(w2e + (size_t)(wave * 32 + j * 8 + lr) * I_DIM + k0 + lcs,
                     lB + (wave * 4 + j) * 512);
        __syncthreads();
#pragma unroll
        for (int kk = 0; kk < BK; kk += 16) {
            int u = (kk >> 3) + (lane >> 5);
            v8s a[2], b[2];
#pragma unroll
            for (int i = 0; i < 2; i++)
                a[i] = *(const v8s*)(lA + swz(wm * 64 + i * 32 + (lane & 31), u));
#pragma unroll
            for (int j = 0; j < 2; j++)
                b[j] = *(const v8s*)(lB + swz(wn * 64 + j * 32 + (lane & 31), u));
#pragma unroll
            for (int i = 0; i < 2; i++)
#pragma unroll
                for (int j = 0; j < 2; j++)
                    acc[i][j] = __builtin_amdgcn_mfma_f32_32x32x16_bf16(a[i], b[j], acc[i][j], 0, 0, 0);
        }
    }

    int half = lane >> 5, c = lane & 31;
#pragma unroll
    for (int i = 0; i < 2; i++)
#pragma unroll
        for (int r = 0; r < 16; r++) {
            int row = wm * 64 + i * 32 + (r & 3) + 8 * (r >> 2) + 4 * half;
            if (row < valid) {
                int pos = row0 + row;
                float coef = pairW[pos];
                unsigned short* orow = ybuf + (size_t)pos * H_DIM + nt * 256;
#pragma unroll
                for (int j = 0; j < 2; j++)
                    orow[wn * 64 + j * 32 + c] = f2bf(coef * acc[i][j][r]);
            }
        }
}

// ---------------- reduce: out[t] = ybuf[pair0(t)] + ybuf[pair1(t)] ----------------
__global__ __launch_bounds__(256)
void k_reduce(const unsigned short* __restrict__ ybuf,
              const int* __restrict__ invMap,
              float* __restrict__ out) {
    int t = blockIdx.x;
    int p0 = invMap[2 * t], p1 = invMap[2 * t + 1];
    int c4 = threadIdx.x * 4;
    ushort4 a = *(const ushort4*)(ybuf + (size_t)p0 * H_DIM + c4);
    ushort4 b = *(const ushort4*)(ybuf + (size_t)p1 * H_DIM + c4);
    float4 o;
    o.x = bf2f(a.x) + bf2f(b.x);
    o.y = bf2f(a.y) + bf2f(b.y);
    o.z = bf2f(a.z) + bf2f(b.z);
    o.w = bf2f(a.w) + bf2f(b.w);
    *(float4*)(out + (size_t)t * H_DIM + c4) = o;
}

extern "C" void kernel_launch(void* const* d_in, const int* in_sizes, int n_in,
                              void* d_out, int out_size, void* d_ws, size_t ws_size,
                              hipStream_t stream) {
    const float* x      = (const float*)d_in[0];
    const float* gating = (const float*)d_in[1];
    const float* w1     = (const float*)d_in[2];
    const float* w2     = (const float*)d_in[3];
    const float* w1s    = (const float*)d_in[4];
    const float* w2s    = (const float*)d_in[5];
    float* out = (float*)d_out;

    char* ws = (char*)d_ws;
    size_t off = 0;
    auto alloc = [&](size_t bytes) { void* p = ws + off; off += (bytes + 255) & ~(size_t)255; return p; };
    unsigned short* xbf  = (unsigned short*)alloc((size_t)T_TOK * H_DIM * 2);             // 32 MB
    unsigned short* w1bf = (unsigned short*)alloc((size_t)E_NUM * 2 * I_DIM * H_DIM * 2); // 32 MB
    unsigned short* w2bf = (unsigned short*)alloc((size_t)E_NUM * H_DIM * I_DIM * 2);     // 16 MB
    unsigned short* hbuf = (unsigned short*)alloc((size_t)NPAIR * I_DIM * 2);             // 64 MB
    unsigned short* ybuf = (unsigned short*)alloc((size_t)NPAIR * H_DIM * 2);             // 64 MB
    int*   pairTok  = (int*)alloc(NPAIR * 4);
    float* pairW    = (float*)alloc(NPAIR * 4);
    int*   tokExp   = (int*)alloc(NPAIR * 4);
    float* tokW     = (float*)alloc(NPAIR * 4);
    int*   invMap   = (int*)alloc(NPAIR * 4);
    int*   counts   = (int*)alloc(64);
    int*   offsets  = (int*)alloc(64);
    int*   tileOff  = (int*)alloc(64);
    int*   cursor   = (int*)alloc(64);

    hipMemsetAsync(counts, 0, 64, stream);

    k_route<<<T_TOK / 256, 256, 0, stream>>>(gating, tokExp, tokW, counts);
    k_scan<<<1, 64, 0, stream>>>(counts, offsets, tileOff, cursor);
    k_scatter<<<T_TOK / 256, 256, 0, stream>>>(tokExp, tokW, cursor, pairTok, pairW, invMap);

    size_t ncvt = ((size_t)T_TOK * H_DIM + (size_t)E_NUM * 2 * I_DIM * H_DIM +
                   (size_t)E_NUM * H_DIM * I_DIM) / 4 / 256;     // 40960 blocks
    k_cvt_all<<<(int)ncvt, 256, 0, stream>>>(x, w1, w2, w1s, w2s, xbf, w1bf, w2bf);

    dim3 g1(MAX_MT, I_DIM / 128);         // 264 x 8
    k_gemm1<<<g1, 256, 0, stream>>>(xbf, w1bf, pairTok, offsets, tileOff, hbuf);
    dim3 g2(MAX_MT, H_DIM / 256);         // 264 x 4
    k_gemm2<<<g2, 512, 0, stream>>>(hbuf, w2bf, pairW, offsets, tileOff, ybuf);
    k_reduce<<<T_TOK, 256, 0, stream>>>(ybuf, invMap, out);
}